// Round 1
// baseline (622.570 us; speedup 1.0000x reference)
//
#include <hip/hip_runtime.h>

#define BATCH 2
#define NTOK 256
#define DM 512
#define NH 8
#define HDIM 64

static __device__ __forceinline__ float fast_silu(float x) {
  return x / (1.0f + __expf(-x));
}

// ---------------- prep: per-token MLP1 projections + Wb2 transpose ----------------
// Sb[b,i,d]  = Wb1[d,:]·c_i + bb1[d]      (query side, bias folded)
// PbT[b,d,j] = Wb1[d,:]·c_j               (key side, transposed for coalescing)
// Sv[b,i,d]  = Wv1[d,:]·c_i + bv1[d]
// Pv[b,j,d]  = Wv1[d,:]·c_j
// Wb2T[d*8+h] = Wb2[h,d]
__global__ __launch_bounds__(256) void prep_pe(
    const float* __restrict__ coords,
    const float* __restrict__ Wb1, const float* __restrict__ bb1,
    const float* __restrict__ Wv1, const float* __restrict__ bv1,
    const float* __restrict__ Wb2,
    float* __restrict__ Sb, float* __restrict__ PbT,
    float* __restrict__ Sv, float* __restrict__ Pv,
    float* __restrict__ Wb2T) {
  int idx = blockIdx.x * 256 + threadIdx.x;   // (b,i,d), d fastest
  int d = idx & (DM - 1);
  int i = (idx >> 9) & (NTOK - 1);
  int b = idx >> 17;
  const float* cp = coords + (b * NTOK + i) * 3;
  float c0 = cp[0], c1 = cp[1], c2 = cp[2];
  float pb = Wb1[d * 3 + 0] * c0 + Wb1[d * 3 + 1] * c1 + Wb1[d * 3 + 2] * c2;
  float pv = Wv1[d * 3 + 0] * c0 + Wv1[d * 3 + 1] * c1 + Wv1[d * 3 + 2] * c2;
  Sb[idx] = pb + bb1[d];
  Sv[idx] = pv + bv1[d];
  Pv[idx] = pv;
  PbT[(b * DM + d) * NTOK + i] = pb;
  if (idx < DM * NH) {
    int h = idx & 7, dd = idx >> 3;
    Wb2T[idx] = Wb2[h * DM + dd];
  }
}

// ---------------- QKV projection GEMM ----------------
// C(M=1024 rows over B*N? no: M=B*N=512, N=1536) = X @ Wqkv^T + bqkv, scattered to
// Q (B,N,512), K (B,H,N,64), V (B,H,N,64)
__global__ __launch_bounds__(256) void qkv_gemm(
    const float* __restrict__ X, const float* __restrict__ W,
    const float* __restrict__ bqkv,
    float* __restrict__ Q, float* __restrict__ K, float* __restrict__ V) {
  __shared__ float Xs[64][33];
  __shared__ float Ws[64][33];
  int t = threadIdx.x;
  int bm = blockIdx.x, bn = blockIdx.y;
  int lrow = t >> 2, lk = (t & 3) * 8;
  const float* Xp = X + (bm * 64 + lrow) * DM + lk;
  const float* Wp = W + (bn * 64 + lrow) * DM + lk;
  int tx = t & 15, ty = t >> 4;
  float acc[4][4] = {};
  for (int k0 = 0; k0 < DM; k0 += 32) {
    float4 xa = *(const float4*)(Xp + k0);
    float4 xb = *(const float4*)(Xp + k0 + 4);
    float4 wa = *(const float4*)(Wp + k0);
    float4 wb = *(const float4*)(Wp + k0 + 4);
    __syncthreads();
    Xs[lrow][lk + 0] = xa.x; Xs[lrow][lk + 1] = xa.y;
    Xs[lrow][lk + 2] = xa.z; Xs[lrow][lk + 3] = xa.w;
    Xs[lrow][lk + 4] = xb.x; Xs[lrow][lk + 5] = xb.y;
    Xs[lrow][lk + 6] = xb.z; Xs[lrow][lk + 7] = xb.w;
    Ws[lrow][lk + 0] = wa.x; Ws[lrow][lk + 1] = wa.y;
    Ws[lrow][lk + 2] = wa.z; Ws[lrow][lk + 3] = wa.w;
    Ws[lrow][lk + 4] = wb.x; Ws[lrow][lk + 5] = wb.y;
    Ws[lrow][lk + 6] = wb.z; Ws[lrow][lk + 7] = wb.w;
    __syncthreads();
#pragma unroll
    for (int kk = 0; kk < 32; ++kk) {
      float a0 = Xs[ty * 4 + 0][kk], a1 = Xs[ty * 4 + 1][kk];
      float a2 = Xs[ty * 4 + 2][kk], a3 = Xs[ty * 4 + 3][kk];
      float b0 = Ws[tx * 4 + 0][kk], b1 = Ws[tx * 4 + 1][kk];
      float b2 = Ws[tx * 4 + 2][kk], b3 = Ws[tx * 4 + 3][kk];
      acc[0][0] = fmaf(a0, b0, acc[0][0]); acc[0][1] = fmaf(a0, b1, acc[0][1]);
      acc[0][2] = fmaf(a0, b2, acc[0][2]); acc[0][3] = fmaf(a0, b3, acc[0][3]);
      acc[1][0] = fmaf(a1, b0, acc[1][0]); acc[1][1] = fmaf(a1, b1, acc[1][1]);
      acc[1][2] = fmaf(a1, b2, acc[1][2]); acc[1][3] = fmaf(a1, b3, acc[1][3]);
      acc[2][0] = fmaf(a2, b0, acc[2][0]); acc[2][1] = fmaf(a2, b1, acc[2][1]);
      acc[2][2] = fmaf(a2, b2, acc[2][2]); acc[2][3] = fmaf(a2, b3, acc[2][3]);
      acc[3][0] = fmaf(a3, b0, acc[3][0]); acc[3][1] = fmaf(a3, b1, acc[3][1]);
      acc[3][2] = fmaf(a3, b2, acc[3][2]); acc[3][3] = fmaf(a3, b3, acc[3][3]);
    }
  }
#pragma unroll
  for (int r = 0; r < 4; ++r) {
    int row = bm * 64 + ty * 4 + r;
    int b = row >> 8, i = row & (NTOK - 1);
#pragma unroll
    for (int c = 0; c < 4; ++c) {
      int n = bn * 64 + tx * 4 + c;
      float val = acc[r][c] + bqkv[n];
      if (n < DM) {
        Q[(b * NTOK + i) * DM + n] = val;
      } else if (n < 2 * DM) {
        int u = n - DM; int h = u >> 6, dp = u & 63;
        K[((b * NH + h) * NTOK + i) * HDIM + dp] = val;
      } else {
        int u = n - 2 * DM; int h = u >> 6, dp = u & 63;
        V[((b * NH + h) * NTOK + i) * HDIM + dp] = val;
      }
    }
  }
}

// ---------------- fused attention: one block per pair of query tokens ----------------
__global__ __launch_bounds__(512) void attn_main(
    const float* __restrict__ Q, const float* __restrict__ K, const float* __restrict__ V,
    const float* __restrict__ Sb, const float* __restrict__ PbT,
    const float* __restrict__ Sv, const float* __restrict__ Pv,
    const float* __restrict__ Wb2T,
    const float* __restrict__ Wv2, const float* __restrict__ bv2,
    float* __restrict__ out) {
  __shared__ float qL[2][DM];
  __shared__ float sbL[2][DM];
  __shared__ float sW[2][NTOK][NH];     // softmax weights, [i-half][j][h]
  __shared__ float gS[2][NH][DM];       // g = sum_j w*hv
  __shared__ float redm[2][NH][4];
  __shared__ float reds[2][NH][4];

  int t = threadIdx.x;
  int blk = blockIdx.x;
  int b = blk >> 7;
  int i0 = (blk & 127) * 2;
  int half = t >> 8;                    // which query of the pair (phase 1)
  int j = t & (NTOK - 1);
  int lane = t & 63;
  int wv_in_half = (t >> 6) & 3;

  // stage q and (Pb_i + bb1) rows for both queries
  {
    const float* qsrc  = Q  + (size_t)(b * NTOK + i0 + half) * DM;
    const float* sbsrc = Sb + (size_t)(b * NTOK + i0 + half) * DM;
    qL[half][j] = qsrc[j];
    qL[half][j + 256] = qsrc[j + 256];
    sbL[half][j] = sbsrc[j];
    sbL[half][j + 256] = sbsrc[j + 256];
  }
  __syncthreads();

  // ---- phase 1: scores (lane = key j) ----
  float qk[NH];
#pragma unroll
  for (int h = 0; h < NH; ++h) qk[h] = 0.f;
  {
    const float* kb = K + (size_t)(b * NH) * NTOK * HDIM + (size_t)j * HDIM;
#pragma unroll
    for (int h = 0; h < NH; ++h) {
      const float* kr = kb + (size_t)h * NTOK * HDIM;
      float acc = 0.f;
#pragma unroll
      for (int dg = 0; dg < HDIM / 4; ++dg) {
        float4 kv = *(const float4*)(kr + dg * 4);
        float4 qv = *(const float4*)&qL[half][h * HDIM + dg * 4];
        acc = fmaf(kv.x, qv.x, acc);
        acc = fmaf(kv.y, qv.y, acc);
        acc = fmaf(kv.z, qv.z, acc);
        acc = fmaf(kv.w, qv.w, acc);
      }
      qk[h] = acc;
    }
  }
  float bias[NH];
#pragma unroll
  for (int h = 0; h < NH; ++h) bias[h] = 0.f;
  {
    const float* pbt = PbT + (size_t)b * DM * NTOK + j;
#pragma unroll 4
    for (int d = 0; d < DM; ++d) {
      float x = sbL[half][d] - pbt[(size_t)d * NTOK];
      float s = fast_silu(x);
      const float* wrow = Wb2T + d * 8;   // thread-uniform -> scalar loads
#pragma unroll
      for (int h = 0; h < NH; ++h) bias[h] = fmaf(s, wrow[h], bias[h]);
    }
  }
  float score[NH], ex[NH];
#pragma unroll
  for (int h = 0; h < NH; ++h) score[h] = qk[h] * 0.125f + bias[h];  // bb2 is softmax-invariant

  // ---- softmax over j (256 lanes = 4 waves per half) ----
#pragma unroll
  for (int h = 0; h < NH; ++h) {
    float m = score[h];
#pragma unroll
    for (int off = 32; off >= 1; off >>= 1) m = fmaxf(m, __shfl_xor(m, off));
    if (lane == 0) redm[half][h][wv_in_half] = m;
  }
  __syncthreads();
#pragma unroll
  for (int h = 0; h < NH; ++h) {
    float m = fmaxf(fmaxf(redm[half][h][0], redm[half][h][1]),
                    fmaxf(redm[half][h][2], redm[half][h][3]));
    float e = __expf(score[h] - m);
    ex[h] = e;
    float s = e;
#pragma unroll
    for (int off = 32; off >= 1; off >>= 1) s += __shfl_xor(s, off);
    if (lane == 0) reds[half][h][wv_in_half] = s;
  }
  __syncthreads();
#pragma unroll
  for (int h = 0; h < NH; ++h) {
    float s = reds[half][h][0] + reds[half][h][1] + reds[half][h][2] + reds[half][h][3];
    sW[half][j][h] = ex[h] / s;
  }
  __syncthreads();

  // ---- phase 2: accumulate g[h][d] and base (lane = feature d, both queries) ----
  int d = t;
  int h_t = t >> 6;        // head of output column o = t (wave-uniform)
  int dp_t = t & 63;
  float sv0 = Sv[(size_t)(b * NTOK + i0) * DM + d];
  float sv1 = Sv[(size_t)(b * NTOK + i0 + 1) * DM + d];
  float g0[NH], g1[NH];
#pragma unroll
  for (int h = 0; h < NH; ++h) { g0[h] = 0.f; g1[h] = 0.f; }
  float base0 = 0.f, base1 = 0.f;
  {
    const float* pv = Pv + (size_t)b * NTOK * DM + d;
    const float* vp = V + (size_t)(b * NH + h_t) * NTOK * HDIM + dp_t;
#pragma unroll 2
    for (int jj = 0; jj < NTOK; ++jj) {
      float pvjd = pv[(size_t)jj * DM];
      float x0 = sv0 - pvjd;
      float x1 = sv1 - pvjd;
      float s0 = fast_silu(x0);
      float s1 = fast_silu(x1);
      float4 wA0 = *(const float4*)&sW[0][jj][0];
      float4 wB0 = *(const float4*)&sW[0][jj][4];
      float4 wA1 = *(const float4*)&sW[1][jj][0];
      float4 wB1 = *(const float4*)&sW[1][jj][4];
      g0[0] = fmaf(s0, wA0.x, g0[0]); g0[1] = fmaf(s0, wA0.y, g0[1]);
      g0[2] = fmaf(s0, wA0.z, g0[2]); g0[3] = fmaf(s0, wA0.w, g0[3]);
      g0[4] = fmaf(s0, wB0.x, g0[4]); g0[5] = fmaf(s0, wB0.y, g0[5]);
      g0[6] = fmaf(s0, wB0.z, g0[6]); g0[7] = fmaf(s0, wB0.w, g0[7]);
      g1[0] = fmaf(s1, wA1.x, g1[0]); g1[1] = fmaf(s1, wA1.y, g1[1]);
      g1[2] = fmaf(s1, wA1.z, g1[2]); g1[3] = fmaf(s1, wA1.w, g1[3]);
      g1[4] = fmaf(s1, wB1.x, g1[4]); g1[5] = fmaf(s1, wB1.y, g1[5]);
      g1[6] = fmaf(s1, wB1.z, g1[6]); g1[7] = fmaf(s1, wB1.w, g1[7]);
      float vval = vp[(size_t)jj * HDIM];
      base0 = fmaf(sW[0][jj][h_t], vval, base0);   // broadcast LDS read
      base1 = fmaf(sW[1][jj][h_t], vval, base1);
    }
  }
#pragma unroll
  for (int h = 0; h < NH; ++h) {
    gS[0][h][d] = g0[h];
    gS[1][h][d] = g1[h];
  }
  __syncthreads();

  // ---- epilogue: out[o=t] = base + g[h]·Wv2[o,:] + bv2[o] for both queries ----
  float acc0 = base0, acc1 = base1;
  {
    const float* wrow = Wv2 + (size_t)t * DM;   // per-lane row stream, L1-friendly
#pragma unroll 2
    for (int dg = 0; dg < DM / 4; ++dg) {
      float4 w4 = *(const float4*)(wrow + dg * 4);
      float4 ga = *(const float4*)&gS[0][h_t][dg * 4];
      float4 gb = *(const float4*)&gS[1][h_t][dg * 4];
      acc0 = fmaf(w4.x, ga.x, acc0); acc0 = fmaf(w4.y, ga.y, acc0);
      acc0 = fmaf(w4.z, ga.z, acc0); acc0 = fmaf(w4.w, ga.w, acc0);
      acc1 = fmaf(w4.x, gb.x, acc1); acc1 = fmaf(w4.y, gb.y, acc1);
      acc1 = fmaf(w4.z, gb.z, acc1); acc1 = fmaf(w4.w, gb.w, acc1);
    }
  }
  float bv = bv2[t];
  out[(size_t)(b * NTOK + i0) * DM + t] = acc0 + bv;
  out[(size_t)(b * NTOK + i0 + 1) * DM + t] = acc1 + bv;
}

extern "C" void kernel_launch(void* const* d_in, const int* in_sizes, int n_in,
                              void* d_out, int out_size, void* d_ws, size_t ws_size,
                              hipStream_t stream) {
  const float* x      = (const float*)d_in[0];
  const float* coords = (const float*)d_in[1];
  const float* Wqkv   = (const float*)d_in[2];
  const float* bqkv   = (const float*)d_in[3];
  const float* Wb1    = (const float*)d_in[4];
  const float* bb1    = (const float*)d_in[5];
  const float* Wb2    = (const float*)d_in[6];
  // d_in[7] = bb2: constant over j per head -> softmax-invariant, unused
  const float* Wv1    = (const float*)d_in[8];
  const float* bv1    = (const float*)d_in[9];
  const float* Wv2    = (const float*)d_in[10];
  const float* bv2    = (const float*)d_in[11];
  float* outp = (float*)d_out;
  float* ws = (float*)d_ws;

  const size_t SZ = (size_t)BATCH * NTOK * DM;   // 262144 floats
  float* Qw   = ws;
  float* Kw   = ws + SZ;
  float* Vw   = ws + 2 * SZ;
  float* Sbw  = ws + 3 * SZ;
  float* PbTw = ws + 4 * SZ;
  float* Svw  = ws + 5 * SZ;
  float* Pvw  = ws + 6 * SZ;
  float* Wb2T = ws + 7 * SZ;                     // + 4096 floats

  hipLaunchKernelGGL(prep_pe, dim3((BATCH * NTOK * DM) / 256), dim3(256), 0, stream,
                     coords, Wb1, d_in[5] ? (const float*)d_in[5] : bb1, Wv1, bv1, Wb2,
                     Sbw, PbTw, Svw, Pvw, Wb2T);
  hipLaunchKernelGGL(qkv_gemm, dim3(8, 24), dim3(256), 0, stream,
                     x, Wqkv, bqkv, Qw, Kw, Vw);
  hipLaunchKernelGGL(attn_main, dim3(BATCH * NTOK / 2), dim3(512), 0, stream,
                     Qw, Kw, Vw, Sbw, PbTw, Svw, Pvw, Wb2T, Wv2, bv2, outp);
}

// Round 2
// 483.214 us; speedup vs baseline: 1.2884x; 1.2884x over previous
//
#include <hip/hip_runtime.h>

#define BATCH 2
#define NTOK 256
#define DM 512
#define NH 8
#define HDIM 64

static __device__ __forceinline__ float fast_silu(float x) {
  // x * rcp(1+exp(-x)) : v_exp + v_rcp, no correctly-rounded divide
  return x * __builtin_amdgcn_rcpf(1.0f + __expf(-x));
}

// ---------------- prep: per-token MLP1 projections + Wb2 transpose ----------------
__global__ __launch_bounds__(256) void prep_pe(
    const float* __restrict__ coords,
    const float* __restrict__ Wb1, const float* __restrict__ bb1,
    const float* __restrict__ Wv1, const float* __restrict__ bv1,
    const float* __restrict__ Wb2,
    float* __restrict__ Sb, float* __restrict__ PbT,
    float* __restrict__ Sv, float* __restrict__ Pv,
    float* __restrict__ Wb2T) {
  int idx = blockIdx.x * 256 + threadIdx.x;   // (b,i,d), d fastest
  int d = idx & (DM - 1);
  int i = (idx >> 9) & (NTOK - 1);
  int b = idx >> 17;
  const float* cp = coords + (b * NTOK + i) * 3;
  float c0 = cp[0], c1 = cp[1], c2 = cp[2];
  float pb = Wb1[d * 3 + 0] * c0 + Wb1[d * 3 + 1] * c1 + Wb1[d * 3 + 2] * c2;
  float pv = Wv1[d * 3 + 0] * c0 + Wv1[d * 3 + 1] * c1 + Wv1[d * 3 + 2] * c2;
  Sb[idx] = pb + bb1[d];
  Sv[idx] = pv + bv1[d];
  Pv[idx] = pv;
  PbT[(b * DM + d) * NTOK + i] = pb;
  if (idx < DM * NH) {
    int h = idx & 7, dd = idx >> 3;
    Wb2T[idx] = Wb2[h * DM + dd];
  }
}

// ---------------- QKV projection GEMM ----------------
__global__ __launch_bounds__(256) void qkv_gemm(
    const float* __restrict__ X, const float* __restrict__ W,
    const float* __restrict__ bqkv,
    float* __restrict__ Q, float* __restrict__ K, float* __restrict__ V) {
  __shared__ float Xs[64][33];
  __shared__ float Ws[64][33];
  int t = threadIdx.x;
  int bm = blockIdx.x, bn = blockIdx.y;
  int lrow = t >> 2, lk = (t & 3) * 8;
  const float* Xp = X + (bm * 64 + lrow) * DM + lk;
  const float* Wp = W + (bn * 64 + lrow) * DM + lk;
  int tx = t & 15, ty = t >> 4;
  float acc[4][4] = {};
  for (int k0 = 0; k0 < DM; k0 += 32) {
    float4 xa = *(const float4*)(Xp + k0);
    float4 xb = *(const float4*)(Xp + k0 + 4);
    float4 wa = *(const float4*)(Wp + k0);
    float4 wb = *(const float4*)(Wp + k0 + 4);
    __syncthreads();
    Xs[lrow][lk + 0] = xa.x; Xs[lrow][lk + 1] = xa.y;
    Xs[lrow][lk + 2] = xa.z; Xs[lrow][lk + 3] = xa.w;
    Xs[lrow][lk + 4] = xb.x; Xs[lrow][lk + 5] = xb.y;
    Xs[lrow][lk + 6] = xb.z; Xs[lrow][lk + 7] = xb.w;
    Ws[lrow][lk + 0] = wa.x; Ws[lrow][lk + 1] = wa.y;
    Ws[lrow][lk + 2] = wa.z; Ws[lrow][lk + 3] = wa.w;
    Ws[lrow][lk + 4] = wb.x; Ws[lrow][lk + 5] = wb.y;
    Ws[lrow][lk + 6] = wb.z; Ws[lrow][lk + 7] = wb.w;
    __syncthreads();
#pragma unroll
    for (int kk = 0; kk < 32; ++kk) {
      float a0 = Xs[ty * 4 + 0][kk], a1 = Xs[ty * 4 + 1][kk];
      float a2 = Xs[ty * 4 + 2][kk], a3 = Xs[ty * 4 + 3][kk];
      float b0 = Ws[tx * 4 + 0][kk], b1 = Ws[tx * 4 + 1][kk];
      float b2 = Ws[tx * 4 + 2][kk], b3 = Ws[tx * 4 + 3][kk];
      acc[0][0] = fmaf(a0, b0, acc[0][0]); acc[0][1] = fmaf(a0, b1, acc[0][1]);
      acc[0][2] = fmaf(a0, b2, acc[0][2]); acc[0][3] = fmaf(a0, b3, acc[0][3]);
      acc[1][0] = fmaf(a1, b0, acc[1][0]); acc[1][1] = fmaf(a1, b1, acc[1][1]);
      acc[1][2] = fmaf(a1, b2, acc[1][2]); acc[1][3] = fmaf(a1, b3, acc[1][3]);
      acc[2][0] = fmaf(a2, b0, acc[2][0]); acc[2][1] = fmaf(a2, b1, acc[2][1]);
      acc[2][2] = fmaf(a2, b2, acc[2][2]); acc[2][3] = fmaf(a2, b3, acc[2][3]);
      acc[3][0] = fmaf(a3, b0, acc[3][0]); acc[3][1] = fmaf(a3, b1, acc[3][1]);
      acc[3][2] = fmaf(a3, b2, acc[3][2]); acc[3][3] = fmaf(a3, b3, acc[3][3]);
    }
  }
#pragma unroll
  for (int r = 0; r < 4; ++r) {
    int row = bm * 64 + ty * 4 + r;
    int b = row >> 8, i = row & (NTOK - 1);
#pragma unroll
    for (int c = 0; c < 4; ++c) {
      int n = bn * 64 + tx * 4 + c;
      float val = acc[r][c] + bqkv[n];
      if (n < DM) {
        Q[(b * NTOK + i) * DM + n] = val;
      } else if (n < 2 * DM) {
        int u = n - DM; int h = u >> 6, dp = u & 63;
        K[((b * NH + h) * NTOK + i) * HDIM + dp] = val;
      } else {
        int u = n - 2 * DM; int h = u >> 6, dp = u & 63;
        V[((b * NH + h) * NTOK + i) * HDIM + dp] = val;
      }
    }
  }
}

// ---------------- fused attention: one block per query token ----------------
// 512 threads = 8 waves. Phase 1: thread (j = t&255, dh = t>>8); the d-loop of the
// bias MLP is split in half across dh, partials reduced through LDS. Each dh group
// also owns 4 heads' qk dot + softmax. Phase 2: thread = feature d (512 lanes).
__global__ __launch_bounds__(512, 4) void attn_main(
    const float* __restrict__ Q, const float* __restrict__ K, const float* __restrict__ V,
    const float* __restrict__ Sb, const float* __restrict__ PbT,
    const float* __restrict__ Sv, const float* __restrict__ Pv,
    const float* __restrict__ Wb2T,
    const float* __restrict__ Wv2, const float* __restrict__ bv2,
    float* __restrict__ out) {
  __shared__ __align__(16) float qL[DM];
  __shared__ __align__(16) float sbL[DM];
  __shared__ float4 red2a[2][NTOK];     // bias partials heads 0-3, [dhalf][j]
  __shared__ float4 red2b[2][NTOK];     // heads 4-7
  __shared__ float4 sWa[NTOK];          // softmax weights heads 0-3 per j
  __shared__ float4 sWb[NTOK];          // heads 4-7
  __shared__ float sWs[NH][NTOK];       // scalar copy for base accumulation
  __shared__ __align__(16) float gS[NH][DM];
  __shared__ float redm[2][4][4];
  __shared__ float reds[2][4][4];

  int t = threadIdx.x;
  // bijective XCD swizzle (512 blocks % 8 == 0): XCD k gets contiguous 64 blocks
  int blk = ((blockIdx.x & 7) << 6) + (blockIdx.x >> 3);   // b*NTOK + i
  int b = blk >> 8;
  int j = t & (NTOK - 1);
  int dh = t >> 8;                      // which d-half this thread sums
  int lane = t & 63;
  int w4 = (t >> 6) & 3;                // wave index within dh group

  qL[t]  = Q [(size_t)blk * DM + t];
  sbL[t] = Sb[(size_t)blk * DM + t];
  __syncthreads();

  // ---- phase 1a: qk for the 4 heads owned by this dh group ----
  float qk[4];
  {
    const float* kb = K + ((size_t)(b * NH + (dh << 2)) * NTOK + j) * HDIM;
#pragma unroll
    for (int c = 0; c < 4; ++c) {
      const float* kr = kb + (size_t)c * NTOK * HDIM;
      const float* qr = qL + ((dh << 2) + c) * HDIM;
      float acc = 0.f;
#pragma unroll
      for (int dg = 0; dg < HDIM / 4; ++dg) {
        float4 kv = *(const float4*)(kr + dg * 4);
        float4 qv = *(const float4*)(qr + dg * 4);
        acc = fmaf(kv.x, qv.x, acc);
        acc = fmaf(kv.y, qv.y, acc);
        acc = fmaf(kv.z, qv.z, acc);
        acc = fmaf(kv.w, qv.w, acc);
      }
      qk[c] = acc;
    }
  }

  // ---- phase 1b: bias MLP partial over d in [dh*256, dh*256+256) ----
  float bp[NH];
#pragma unroll
  for (int h = 0; h < NH; ++h) bp[h] = 0.f;
  {
    const float* pbt = PbT + (size_t)b * DM * NTOK + (size_t)(dh << 8) * NTOK + j;
    const float* sb = sbL + (dh << 8);
    const float* wb = Wb2T + (dh << 8) * NH;
#pragma unroll 4
    for (int d = 0; d < 256; ++d) {
      float x = sb[d] - pbt[(size_t)d * NTOK];
      float s = fast_silu(x);
      const float* wrow = wb + d * NH;    // thread-uniform -> scalar loads
#pragma unroll
      for (int h = 0; h < NH; ++h) bp[h] = fmaf(s, wrow[h], bp[h]);
    }
  }
  red2a[dh][j] = make_float4(bp[0], bp[1], bp[2], bp[3]);
  red2b[dh][j] = make_float4(bp[4], bp[5], bp[6], bp[7]);
  __syncthreads();

  // ---- combine partials; scores for heads hh = dh*4+c ----
  float score[4], ex[4];
  {
    const float4* sel = dh ? &red2b[0][0] : &red2a[0][0];
    float4 ra = sel[j];           // [0][j]
    float4 rb = sel[NTOK + j];    // [1][j]
    score[0] = qk[0] * 0.125f + ra.x + rb.x;
    score[1] = qk[1] * 0.125f + ra.y + rb.y;
    score[2] = qk[2] * 0.125f + ra.z + rb.z;
    score[3] = qk[3] * 0.125f + ra.w + rb.w;    // bb2 softmax-invariant, dropped
  }

  // ---- softmax over j (4 waves per dh group) ----
#pragma unroll
  for (int c = 0; c < 4; ++c) {
    float m = score[c];
#pragma unroll
    for (int off = 32; off >= 1; off >>= 1) m = fmaxf(m, __shfl_xor(m, off));
    if (lane == 0) redm[dh][c][w4] = m;
  }
  __syncthreads();
#pragma unroll
  for (int c = 0; c < 4; ++c) {
    float m = fmaxf(fmaxf(redm[dh][c][0], redm[dh][c][1]),
                    fmaxf(redm[dh][c][2], redm[dh][c][3]));
    float e = __expf(score[c] - m);
    ex[c] = e;
    float s = e;
#pragma unroll
    for (int off = 32; off >= 1; off >>= 1) s += __shfl_xor(s, off);
    if (lane == 0) reds[dh][c][w4] = s;
  }
  __syncthreads();
  {
    float4 w;
    float s0 = reds[dh][0][0] + reds[dh][0][1] + reds[dh][0][2] + reds[dh][0][3];
    float s1 = reds[dh][1][0] + reds[dh][1][1] + reds[dh][1][2] + reds[dh][1][3];
    float s2 = reds[dh][2][0] + reds[dh][2][1] + reds[dh][2][2] + reds[dh][2][3];
    float s3 = reds[dh][3][0] + reds[dh][3][1] + reds[dh][3][2] + reds[dh][3][3];
    w.x = ex[0] * __builtin_amdgcn_rcpf(s0);
    w.y = ex[1] * __builtin_amdgcn_rcpf(s1);
    w.z = ex[2] * __builtin_amdgcn_rcpf(s2);
    w.w = ex[3] * __builtin_amdgcn_rcpf(s3);
    if (dh == 0) sWa[j] = w; else sWb[j] = w;
    int hb = dh << 2;
    sWs[hb + 0][j] = w.x;
    sWs[hb + 1][j] = w.y;
    sWs[hb + 2][j] = w.z;
    sWs[hb + 3][j] = w.w;
  }
  __syncthreads();

  // ---- phase 2: accumulate g[h][d] and base (lane = feature d) ----
  int d = t;
  int h_t = t >> 6;        // head of output column o = t (wave-uniform)
  int dp_t = t & 63;
  float sv = Sv[(size_t)blk * DM + d];
  float g[NH];
#pragma unroll
  for (int h = 0; h < NH; ++h) g[h] = 0.f;
  float base = 0.f;
  {
    const float* pv = Pv + (size_t)b * NTOK * DM + d;
    const float* vp = V + (size_t)(b * NH + h_t) * NTOK * HDIM + dp_t;
#pragma unroll 4
    for (int jj = 0; jj < NTOK; ++jj) {
      float pvjd = pv[(size_t)jj * DM];
      float s = fast_silu(sv - pvjd);
      float4 wA = sWa[jj];
      float4 wB = sWb[jj];
      g[0] = fmaf(s, wA.x, g[0]); g[1] = fmaf(s, wA.y, g[1]);
      g[2] = fmaf(s, wA.z, g[2]); g[3] = fmaf(s, wA.w, g[3]);
      g[4] = fmaf(s, wB.x, g[4]); g[5] = fmaf(s, wB.y, g[5]);
      g[6] = fmaf(s, wB.z, g[6]); g[7] = fmaf(s, wB.w, g[7]);
      float vval = vp[(size_t)jj * HDIM];
      base = fmaf(sWs[h_t][jj], vval, base);   // broadcast LDS read
    }
  }
#pragma unroll
  for (int h = 0; h < NH; ++h) gS[h][d] = g[h];
  __syncthreads();

  // ---- epilogue: out[o=t] = base + g[h_t]·Wv2[o,:] + bv2[o] ----
  float acc = base;
  {
    const float* wrow = Wv2 + (size_t)t * DM;
#pragma unroll 2
    for (int dg = 0; dg < DM / 4; ++dg) {
      float4 w4v = *(const float4*)(wrow + dg * 4);
      float4 ga = *(const float4*)&gS[h_t][dg * 4];
      acc = fmaf(w4v.x, ga.x, acc); acc = fmaf(w4v.y, ga.y, acc);
      acc = fmaf(w4v.z, ga.z, acc); acc = fmaf(w4v.w, ga.w, acc);
    }
  }
  out[(size_t)blk * DM + t] = acc + bv2[t];
}

extern "C" void kernel_launch(void* const* d_in, const int* in_sizes, int n_in,
                              void* d_out, int out_size, void* d_ws, size_t ws_size,
                              hipStream_t stream) {
  const float* x      = (const float*)d_in[0];
  const float* coords = (const float*)d_in[1];
  const float* Wqkv   = (const float*)d_in[2];
  const float* bqkv   = (const float*)d_in[3];
  const float* Wb1    = (const float*)d_in[4];
  const float* bb1    = (const float*)d_in[5];
  const float* Wb2    = (const float*)d_in[6];
  // d_in[7] = bb2: softmax-invariant, unused
  const float* Wv1    = (const float*)d_in[8];
  const float* bv1    = (const float*)d_in[9];
  const float* Wv2    = (const float*)d_in[10];
  const float* bv2    = (const float*)d_in[11];
  float* outp = (float*)d_out;
  float* ws = (float*)d_ws;

  const size_t SZ = (size_t)BATCH * NTOK * DM;   // 262144 floats
  float* Qw   = ws;
  float* Kw   = ws + SZ;
  float* Vw   = ws + 2 * SZ;
  float* Sbw  = ws + 3 * SZ;
  float* PbTw = ws + 4 * SZ;
  float* Svw  = ws + 5 * SZ;
  float* Pvw  = ws + 6 * SZ;
  float* Wb2T = ws + 7 * SZ;                     // + 4096 floats

  hipLaunchKernelGGL(prep_pe, dim3((BATCH * NTOK * DM) / 256), dim3(256), 0, stream,
                     coords, Wb1, bb1, Wv1, bv1, Wb2,
                     Sbw, PbTw, Svw, Pvw, Wb2T);
  hipLaunchKernelGGL(qkv_gemm, dim3(8, 24), dim3(256), 0, stream,
                     x, Wqkv, bqkv, Qw, Kw, Vw);
  hipLaunchKernelGGL(attn_main, dim3(BATCH * NTOK), dim3(512), 0, stream,
                     Qw, Kw, Vw, Sbw, PbTw, Svw, Pvw, Wb2T, Wv2, bv2, outp);
}

// Round 3
// 373.533 us; speedup vs baseline: 1.6667x; 1.2936x over previous
//
#include <hip/hip_runtime.h>

#define BATCH 2
#define NTOK 256
#define DM 512
#define NH 8
#define HDIM 64

typedef unsigned int uint32;
typedef unsigned short ushort16;

static __device__ __forceinline__ float fast_silu(float x) {
  // x * rcp(1+exp(-x)) : v_exp + v_rcp, no correctly-rounded divide
  return x * __builtin_amdgcn_rcpf(1.0f + __expf(-x));
}
static __device__ __forceinline__ ushort16 bf16_rne(float x) {
  uint32 u = __float_as_uint(x);
  u += 0x7fffu + ((u >> 16) & 1u);
  return (ushort16)(u >> 16);
}
static __device__ __forceinline__ float bf16_lo(uint32 u) {
  return __uint_as_float(u << 16);
}
static __device__ __forceinline__ float bf16_hi(uint32 u) {
  return __uint_as_float(u & 0xffff0000u);
}

// ---------------- prep: per-token MLP1 projections (bf16 packed) + Wb2^T ----------------
// Sb[b,i,d] = Wb1[d,:]*c_i + bb1[d]  (fp32, query side)
// Sv[b,i,d] = Wv1[d,:]*c_i + bv1[d]  (fp32, query side)
// PbT8: bf16, [b][d>>3][j][d&7]   (16B per 8 d-elems per j, for phase 1b)
// PvQ : bf16, [b][j>>2][d][j&3]   (8B per 4 j-elems per d, for phase 2)
__global__ __launch_bounds__(256) void prep_pe(
    const float* __restrict__ coords,
    const float* __restrict__ Wb1, const float* __restrict__ bb1,
    const float* __restrict__ Wv1, const float* __restrict__ bv1,
    const float* __restrict__ Wb2,
    float* __restrict__ Sb, float* __restrict__ Sv,
    ushort16* __restrict__ PbT8, ushort16* __restrict__ PvQ,
    float* __restrict__ Wb2T) {
  int idx = blockIdx.x * 256 + threadIdx.x;   // (b,i,d), d fastest
  int d = idx & (DM - 1);
  int i = (idx >> 9) & (NTOK - 1);
  int b = idx >> 17;
  const float* cp = coords + (b * NTOK + i) * 3;
  float c0 = cp[0], c1 = cp[1], c2 = cp[2];
  float pb = Wb1[d * 3 + 0] * c0 + Wb1[d * 3 + 1] * c1 + Wb1[d * 3 + 2] * c2;
  float pv = Wv1[d * 3 + 0] * c0 + Wv1[d * 3 + 1] * c1 + Wv1[d * 3 + 2] * c2;
  Sb[idx] = pb + bb1[d];
  Sv[idx] = pv + bv1[d];
  PbT8[(((size_t)(b << 6) + (d >> 3)) * NTOK + i) * 8 + (d & 7)] = bf16_rne(pb);
  PvQ[(((size_t)(b << 6) + (i >> 2)) * DM + d) * 4 + (i & 3)] = bf16_rne(pv);
  if (idx < DM * NH) {
    int h = idx & 7, dd = idx >> 3;
    Wb2T[idx] = Wb2[h * DM + dd];
  }
}

// ---------------- QKV projection GEMM ----------------
__global__ __launch_bounds__(256) void qkv_gemm(
    const float* __restrict__ X, const float* __restrict__ W,
    const float* __restrict__ bqkv,
    float* __restrict__ Q, float* __restrict__ K, float* __restrict__ V) {
  __shared__ float Xs[64][33];
  __shared__ float Ws[64][33];
  int t = threadIdx.x;
  int bm = blockIdx.x, bn = blockIdx.y;
  int lrow = t >> 2, lk = (t & 3) * 8;
  const float* Xp = X + (bm * 64 + lrow) * DM + lk;
  const float* Wp = W + (bn * 64 + lrow) * DM + lk;
  int tx = t & 15, ty = t >> 4;
  float acc[4][4] = {};
  for (int k0 = 0; k0 < DM; k0 += 32) {
    float4 xa = *(const float4*)(Xp + k0);
    float4 xb = *(const float4*)(Xp + k0 + 4);
    float4 wa = *(const float4*)(Wp + k0);
    float4 wb = *(const float4*)(Wp + k0 + 4);
    __syncthreads();
    Xs[lrow][lk + 0] = xa.x; Xs[lrow][lk + 1] = xa.y;
    Xs[lrow][lk + 2] = xa.z; Xs[lrow][lk + 3] = xa.w;
    Xs[lrow][lk + 4] = xb.x; Xs[lrow][lk + 5] = xb.y;
    Xs[lrow][lk + 6] = xb.z; Xs[lrow][lk + 7] = xb.w;
    Ws[lrow][lk + 0] = wa.x; Ws[lrow][lk + 1] = wa.y;
    Ws[lrow][lk + 2] = wa.z; Ws[lrow][lk + 3] = wa.w;
    Ws[lrow][lk + 4] = wb.x; Ws[lrow][lk + 5] = wb.y;
    Ws[lrow][lk + 6] = wb.z; Ws[lrow][lk + 7] = wb.w;
    __syncthreads();
#pragma unroll
    for (int kk = 0; kk < 32; ++kk) {
      float a0 = Xs[ty * 4 + 0][kk], a1 = Xs[ty * 4 + 1][kk];
      float a2 = Xs[ty * 4 + 2][kk], a3 = Xs[ty * 4 + 3][kk];
      float b0 = Ws[tx * 4 + 0][kk], b1 = Ws[tx * 4 + 1][kk];
      float b2 = Ws[tx * 4 + 2][kk], b3 = Ws[tx * 4 + 3][kk];
      acc[0][0] = fmaf(a0, b0, acc[0][0]); acc[0][1] = fmaf(a0, b1, acc[0][1]);
      acc[0][2] = fmaf(a0, b2, acc[0][2]); acc[0][3] = fmaf(a0, b3, acc[0][3]);
      acc[1][0] = fmaf(a1, b0, acc[1][0]); acc[1][1] = fmaf(a1, b1, acc[1][1]);
      acc[1][2] = fmaf(a1, b2, acc[1][2]); acc[1][3] = fmaf(a1, b3, acc[1][3]);
      acc[2][0] = fmaf(a2, b0, acc[2][0]); acc[2][1] = fmaf(a2, b1, acc[2][1]);
      acc[2][2] = fmaf(a2, b2, acc[2][2]); acc[2][3] = fmaf(a2, b3, acc[2][3]);
      acc[3][0] = fmaf(a3, b0, acc[3][0]); acc[3][1] = fmaf(a3, b1, acc[3][1]);
      acc[3][2] = fmaf(a3, b2, acc[3][2]); acc[3][3] = fmaf(a3, b3, acc[3][3]);
    }
  }
#pragma unroll
  for (int r = 0; r < 4; ++r) {
    int row = bm * 64 + ty * 4 + r;
    int b = row >> 8, i = row & (NTOK - 1);
#pragma unroll
    for (int c = 0; c < 4; ++c) {
      int n = bn * 64 + tx * 4 + c;
      float val = acc[r][c] + bqkv[n];
      if (n < DM) {
        Q[(b * NTOK + i) * DM + n] = val;
      } else if (n < 2 * DM) {
        int u = n - DM; int h = u >> 6, dp = u & 63;
        K[((b * NH + h) * NTOK + i) * HDIM + dp] = val;
      } else {
        int u = n - 2 * DM; int h = u >> 6, dp = u & 63;
        V[((b * NH + h) * NTOK + i) * HDIM + dp] = val;
      }
    }
  }
}

// ---------------- attention part: scores + softmax + g accumulation ----------------
// One block per query. 512 thr = 8 waves. Phase 1: (j = t&255, dh = t>>8) with the
// bias-MLP d-loop split across dh. Phase 2: thread = feature d. Writes softmax
// weights (Wsm, fp32) and g (Gbf, bf16) for the out_gemm kernel; no Wv2/V here.
__global__ __launch_bounds__(512, 4) void attn_part(
    const float* __restrict__ Q, const float* __restrict__ K,
    const float* __restrict__ Sb, const float* __restrict__ Sv,
    const ushort16* __restrict__ PbT8, const ushort16* __restrict__ PvQ,
    const float* __restrict__ Wb2T,
    float* __restrict__ Wsm, ushort16* __restrict__ Gbf) {
  __shared__ __align__(16) float qL[DM];
  __shared__ __align__(16) float sbL[DM];
  __shared__ __align__(16) float uni[4096];   // 16 KB: red2 (ph1) then sWa/sWb (ph2)
  __shared__ float redm[2][4][4];
  __shared__ float reds[2][4][4];

  int t = threadIdx.x;
  // bijective XCD swizzle: XCD k gets 64 contiguous queries (single batch)
  int blk = ((blockIdx.x & 7) << 6) + (blockIdx.x >> 3);   // b*NTOK + i
  int b = blk >> 8;
  int qi = blk & (NTOK - 1);
  int j = t & (NTOK - 1);
  int dh = t >> 8;
  int dhu = __builtin_amdgcn_readfirstlane(dh);  // wave-uniform -> scalar addressing
  int lane = t & 63;
  int w4 = (t >> 6) & 3;

  qL[t]  = Q [(size_t)blk * DM + t];
  sbL[t] = Sb[(size_t)blk * DM + t];
  __syncthreads();

  // ---- phase 1a: qk for the 4 heads owned by this dh group ----
  float qk[4];
  {
    const float* kb = K + ((size_t)(b * NH + (dhu << 2)) * NTOK + j) * HDIM;
    const float* qb = qL + (dhu << 8);
#pragma unroll
    for (int c = 0; c < 4; ++c) {
      const float* kr = kb + (size_t)c * NTOK * HDIM;
      const float* qr = qb + c * HDIM;
      float acc = 0.f;
#pragma unroll
      for (int dg = 0; dg < HDIM / 4; ++dg) {
        float4 kv = *(const float4*)(kr + dg * 4);
        float4 qv = *(const float4*)(qr + dg * 4);
        acc = fmaf(kv.x, qv.x, acc);
        acc = fmaf(kv.y, qv.y, acc);
        acc = fmaf(kv.z, qv.z, acc);
        acc = fmaf(kv.w, qv.w, acc);
      }
      qk[c] = acc;
    }
  }

  // ---- phase 1b: bias MLP partial over this dh group's 256 d ----
  float bp[NH];
#pragma unroll
  for (int h = 0; h < NH; ++h) bp[h] = 0.f;
  {
    const ushort16* pb8 = PbT8 + (((size_t)(b << 6) + (dhu << 5)) * NTOK + j) * 8;
    const float* sb = sbL + (dhu << 8);
    const float* wb = Wb2T + (dhu << 8) * NH;   // uniform base -> s_load
#pragma unroll 2
    for (int gg = 0; gg < 32; ++gg) {
      uint4 pk = *(const uint4*)(pb8 + (size_t)gg * (NTOK * 8));  // 8 bf16
      float4 sv0 = *(const float4*)(sb + gg * 8);
      float4 sv1 = *(const float4*)(sb + gg * 8 + 4);
      float s0 = fast_silu(sv0.x - bf16_lo(pk.x));
      float s1 = fast_silu(sv0.y - bf16_hi(pk.x));
      float s2 = fast_silu(sv0.z - bf16_lo(pk.y));
      float s3 = fast_silu(sv0.w - bf16_hi(pk.y));
      float s4 = fast_silu(sv1.x - bf16_lo(pk.z));
      float s5 = fast_silu(sv1.y - bf16_hi(pk.z));
      float s6 = fast_silu(sv1.z - bf16_lo(pk.w));
      float s7 = fast_silu(sv1.w - bf16_hi(pk.w));
      const float* w0 = wb + gg * 8 * NH;
#pragma unroll
      for (int h = 0; h < NH; ++h) {
        float a = fmaf(s0, w0[h], s1 * w0[NH + h]);
        float c = fmaf(s2, w0[2 * NH + h], s3 * w0[3 * NH + h]);
        float e = fmaf(s4, w0[4 * NH + h], s5 * w0[5 * NH + h]);
        float f = fmaf(s6, w0[6 * NH + h], s7 * w0[7 * NH + h]);
        bp[h] += (a + c) + (e + f);
      }
    }
  }
  {
    float4* red2a = (float4*)uni;         // [dh][j] heads 0-3
    float4* red2b = red2a + 512;          // [dh][j] heads 4-7
    red2a[dh * NTOK + j] = make_float4(bp[0], bp[1], bp[2], bp[3]);
    red2b[dh * NTOK + j] = make_float4(bp[4], bp[5], bp[6], bp[7]);
  }
  __syncthreads();

  // ---- combine partials; scores for heads dh*4+c ----
  float score[4], ex[4];
  {
    const float4* red2a = (const float4*)uni;
    const float4* red2b = red2a + 512;
    const float4* sel = dh ? red2b : red2a;
    float4 ra = sel[j];
    float4 rb = sel[NTOK + j];
    score[0] = qk[0] * 0.125f + ra.x + rb.x;
    score[1] = qk[1] * 0.125f + ra.y + rb.y;
    score[2] = qk[2] * 0.125f + ra.z + rb.z;
    score[3] = qk[3] * 0.125f + ra.w + rb.w;   // bb2 softmax-invariant, dropped
  }

  // ---- softmax over j ----
#pragma unroll
  for (int c = 0; c < 4; ++c) {
    float m = score[c];
#pragma unroll
    for (int off = 32; off >= 1; off >>= 1) m = fmaxf(m, __shfl_xor(m, off));
    if (lane == 0) redm[dh][c][w4] = m;
  }
  __syncthreads();
#pragma unroll
  for (int c = 0; c < 4; ++c) {
    float m = fmaxf(fmaxf(redm[dh][c][0], redm[dh][c][1]),
                    fmaxf(redm[dh][c][2], redm[dh][c][3]));
    float e = __expf(score[c] - m);
    ex[c] = e;
    float s = e;
#pragma unroll
    for (int off = 32; off >= 1; off >>= 1) s += __shfl_xor(s, off);
    if (lane == 0) reds[dh][c][w4] = s;
  }
  __syncthreads();
  {
    float4 w;
    float s0 = reds[dh][0][0] + reds[dh][0][1] + reds[dh][0][2] + reds[dh][0][3];
    float s1 = reds[dh][1][0] + reds[dh][1][1] + reds[dh][1][2] + reds[dh][1][3];
    float s2 = reds[dh][2][0] + reds[dh][2][1] + reds[dh][2][2] + reds[dh][2][3];
    float s3 = reds[dh][3][0] + reds[dh][3][1] + reds[dh][3][2] + reds[dh][3][3];
    w.x = ex[0] * __builtin_amdgcn_rcpf(s0);
    w.y = ex[1] * __builtin_amdgcn_rcpf(s1);
    w.z = ex[2] * __builtin_amdgcn_rcpf(s2);
    w.w = ex[3] * __builtin_amdgcn_rcpf(s3);
    // stash for phase 2 (aliases red2: two barriers since last red2 read)
    float4* sWa = (float4*)uni;
    float4* sWb = sWa + 256;
    if (dh == 0) sWa[j] = w; else sWb[j] = w;
    // write softmax weights for out_gemm's base GEMM: Wsm[b][h][i][j]
    float* wout = Wsm + (((size_t)(b * NH + (dh << 2)) * NTOK + qi) * NTOK) + j;
    wout[0] = w.x;
    wout[(size_t)NTOK * NTOK] = w.y;
    wout[2 * (size_t)NTOK * NTOK] = w.z;
    wout[3 * (size_t)NTOK * NTOK] = w.w;
  }
  __syncthreads();

  // ---- phase 2: accumulate g[h][d] (lane = feature d) ----
  {
    int d = t;
    float sv = Sv[(size_t)blk * DM + d];
    float g[NH];
#pragma unroll
    for (int h = 0; h < NH; ++h) g[h] = 0.f;
    const float4* sWa = (const float4*)uni;
    const float4* sWb = sWa + 256;
    const ushort16* pq = PvQ + ((size_t)(b << 6) * DM + d) * 4;
#pragma unroll 2
    for (int jq = 0; jq < 64; ++jq) {
      uint2 pk = *(const uint2*)(pq + (size_t)jq * (DM * 4));  // 4 bf16 (4 j's)
      float s0 = fast_silu(sv - bf16_lo(pk.x));
      float s1 = fast_silu(sv - bf16_hi(pk.x));
      float s2 = fast_silu(sv - bf16_lo(pk.y));
      float s3 = fast_silu(sv - bf16_hi(pk.y));
      int j0 = jq * 4;
      float4 a0 = sWa[j0 + 0], b0 = sWb[j0 + 0];
      float4 a1 = sWa[j0 + 1], b1 = sWb[j0 + 1];
      float4 a2 = sWa[j0 + 2], b2 = sWb[j0 + 2];
      float4 a3 = sWa[j0 + 3], b3 = sWb[j0 + 3];
      g[0] = fmaf(s0, a0.x, g[0]); g[1] = fmaf(s0, a0.y, g[1]);
      g[2] = fmaf(s0, a0.z, g[2]); g[3] = fmaf(s0, a0.w, g[3]);
      g[4] = fmaf(s0, b0.x, g[4]); g[5] = fmaf(s0, b0.y, g[5]);
      g[6] = fmaf(s0, b0.z, g[6]); g[7] = fmaf(s0, b0.w, g[7]);
      g[0] = fmaf(s1, a1.x, g[0]); g[1] = fmaf(s1, a1.y, g[1]);
      g[2] = fmaf(s1, a1.z, g[2]); g[3] = fmaf(s1, a1.w, g[3]);
      g[4] = fmaf(s1, b1.x, g[4]); g[5] = fmaf(s1, b1.y, g[5]);
      g[6] = fmaf(s1, b1.z, g[6]); g[7] = fmaf(s1, b1.w, g[7]);
      g[0] = fmaf(s2, a2.x, g[0]); g[1] = fmaf(s2, a2.y, g[1]);
      g[2] = fmaf(s2, a2.z, g[2]); g[3] = fmaf(s2, a2.w, g[3]);
      g[4] = fmaf(s2, b2.x, g[4]); g[5] = fmaf(s2, b2.y, g[5]);
      g[6] = fmaf(s2, b2.z, g[6]); g[7] = fmaf(s2, b2.w, g[7]);
      g[0] = fmaf(s3, a3.x, g[0]); g[1] = fmaf(s3, a3.y, g[1]);
      g[2] = fmaf(s3, a3.z, g[2]); g[3] = fmaf(s3, a3.w, g[3]);
      g[4] = fmaf(s3, b3.x, g[4]); g[5] = fmaf(s3, b3.y, g[5]);
      g[6] = fmaf(s3, b3.z, g[6]); g[7] = fmaf(s3, b3.w, g[7]);
    }
#pragma unroll
    for (int h = 0; h < NH; ++h)
      Gbf[((size_t)blk * NH + h) * DM + d] = bf16_rne(g[h]);
  }
}

// ---------------- out GEMM: out = Wsm @ V + G @ Wv2^T + bv2, per head ----------------
// grid (8 i-tiles, 8 heads), 256 thr, 64x64 tile, 4x4 micro.
__global__ __launch_bounds__(256) void out_gemm(
    const ushort16* __restrict__ Gbf, const float* __restrict__ Wsm,
    const float* __restrict__ Wv2, const float* __restrict__ V,
    const float* __restrict__ bv2, float* __restrict__ out) {
  __shared__ float As[64][33];
  __shared__ float Bs[64][33];
  int t = threadIdx.x;
  int bm = blockIdx.x;       // 64-query tile
  int h = blockIdx.y;        // head
  int b = bm >> 2;
  int lrow = t >> 2, lk = (t & 3) * 8;
  int tx = t & 15, ty = t >> 4;
  float acc[4][4] = {};

  // ---- GEMM1: G(i x d) @ Wv2_h^T, K = 512 ----
  {
    const ushort16* Arow = Gbf + ((size_t)(bm * 64 + lrow) * NH + h) * DM + lk;
    const float* Brow = Wv2 + (size_t)(h * 64 + lrow) * DM + lk;
    for (int k0 = 0; k0 < DM; k0 += 32) {
      uint4 ga = *(const uint4*)(Arow + k0);
      float4 wa = *(const float4*)(Brow + k0);
      float4 wbv = *(const float4*)(Brow + k0 + 4);
      __syncthreads();
      As[lrow][lk + 0] = bf16_lo(ga.x); As[lrow][lk + 1] = bf16_hi(ga.x);
      As[lrow][lk + 2] = bf16_lo(ga.y); As[lrow][lk + 3] = bf16_hi(ga.y);
      As[lrow][lk + 4] = bf16_lo(ga.z); As[lrow][lk + 5] = bf16_hi(ga.z);
      As[lrow][lk + 6] = bf16_lo(ga.w); As[lrow][lk + 7] = bf16_hi(ga.w);
      Bs[lrow][lk + 0] = wa.x;  Bs[lrow][lk + 1] = wa.y;
      Bs[lrow][lk + 2] = wa.z;  Bs[lrow][lk + 3] = wa.w;
      Bs[lrow][lk + 4] = wbv.x; Bs[lrow][lk + 5] = wbv.y;
      Bs[lrow][lk + 6] = wbv.z; Bs[lrow][lk + 7] = wbv.w;
      __syncthreads();
#pragma unroll
      for (int kk = 0; kk < 32; ++kk) {
        float a0 = As[ty * 4 + 0][kk], a1 = As[ty * 4 + 1][kk];
        float a2 = As[ty * 4 + 2][kk], a3 = As[ty * 4 + 3][kk];
        float b0 = Bs[tx * 4 + 0][kk], b1 = Bs[tx * 4 + 1][kk];
        float b2 = Bs[tx * 4 + 2][kk], b3 = Bs[tx * 4 + 3][kk];
        acc[0][0] = fmaf(a0, b0, acc[0][0]); acc[0][1] = fmaf(a0, b1, acc[0][1]);
        acc[0][2] = fmaf(a0, b2, acc[0][2]); acc[0][3] = fmaf(a0, b3, acc[0][3]);
        acc[1][0] = fmaf(a1, b0, acc[1][0]); acc[1][1] = fmaf(a1, b1, acc[1][1]);
        acc[1][2] = fmaf(a1, b2, acc[1][2]); acc[1][3] = fmaf(a1, b3, acc[1][3]);
        acc[2][0] = fmaf(a2, b0, acc[2][0]); acc[2][1] = fmaf(a2, b1, acc[2][1]);
        acc[2][2] = fmaf(a2, b2, acc[2][2]); acc[2][3] = fmaf(a2, b3, acc[2][3]);
        acc[3][0] = fmaf(a3, b0, acc[3][0]); acc[3][1] = fmaf(a3, b1, acc[3][1]);
        acc[3][2] = fmaf(a3, b2, acc[3][2]); acc[3][3] = fmaf(a3, b3, acc[3][3]);
      }
    }
  }

  // ---- GEMM2: Wsm(i x j) @ V(j x dp), K = 256 ----
  {
    const float* A2row = Wsm + (((size_t)(b * NH + h) * NTOK) + ((bm * 64 + lrow) & (NTOK - 1))) * NTOK + lk;
    int lrow2 = t >> 3, lc = (t & 7) * 8;
    const float* Vrow = V + ((size_t)(b * NH + h) * NTOK + lrow2) * HDIM + lc;
    float (*Vs)[65] = (float(*)[65])&Bs[0][0];   // 32x65 = 2080 <= 64x33
    for (int k0 = 0; k0 < NTOK; k0 += 32) {
      float4 a1 = *(const float4*)(A2row + k0);
      float4 a2 = *(const float4*)(A2row + k0 + 4);
      float4 v1 = *(const float4*)(Vrow + (size_t)k0 * HDIM);
      float4 v2 = *(const float4*)(Vrow + (size_t)k0 * HDIM + 4);
      __syncthreads();
      As[lrow][lk + 0] = a1.x; As[lrow][lk + 1] = a1.y;
      As[lrow][lk + 2] = a1.z; As[lrow][lk + 3] = a1.w;
      As[lrow][lk + 4] = a2.x; As[lrow][lk + 5] = a2.y;
      As[lrow][lk + 6] = a2.z; As[lrow][lk + 7] = a2.w;
      Vs[lrow2][lc + 0] = v1.x; Vs[lrow2][lc + 1] = v1.y;
      Vs[lrow2][lc + 2] = v1.z; Vs[lrow2][lc + 3] = v1.w;
      Vs[lrow2][lc + 4] = v2.x; Vs[lrow2][lc + 5] = v2.y;
      Vs[lrow2][lc + 6] = v2.z; Vs[lrow2][lc + 7] = v2.w;
      __syncthreads();
#pragma unroll
      for (int kk = 0; kk < 32; ++kk) {
        float a0 = As[ty * 4 + 0][kk], a1v = As[ty * 4 + 1][kk];
        float a2v = As[ty * 4 + 2][kk], a3v = As[ty * 4 + 3][kk];
        float4 bvv = *(const float4*)&Vs[kk][tx * 4];
        acc[0][0] = fmaf(a0, bvv.x, acc[0][0]); acc[0][1] = fmaf(a0, bvv.y, acc[0][1]);
        acc[0][2] = fmaf(a0, bvv.z, acc[0][2]); acc[0][3] = fmaf(a0, bvv.w, acc[0][3]);
        acc[1][0] = fmaf(a1v, bvv.x, acc[1][0]); acc[1][1] = fmaf(a1v, bvv.y, acc[1][1]);
        acc[1][2] = fmaf(a1v, bvv.z, acc[1][2]); acc[1][3] = fmaf(a1v, bvv.w, acc[1][3]);
        acc[2][0] = fmaf(a2v, bvv.x, acc[2][0]); acc[2][1] = fmaf(a2v, bvv.y, acc[2][1]);
        acc[2][2] = fmaf(a2v, bvv.z, acc[2][2]); acc[2][3] = fmaf(a2v, bvv.w, acc[2][3]);
        acc[3][0] = fmaf(a3v, bvv.x, acc[3][0]); acc[3][1] = fmaf(a3v, bvv.y, acc[3][1]);
        acc[3][2] = fmaf(a3v, bvv.z, acc[3][2]); acc[3][3] = fmaf(a3v, bvv.w, acc[3][3]);
      }
    }
  }

  // ---- epilogue ----
  int o0 = h * 64 + tx * 4;
  float4 bvq = *(const float4*)(bv2 + o0);
#pragma unroll
  for (int r = 0; r < 4; ++r) {
    int bi = bm * 64 + ty * 4 + r;
    float4 res;
    res.x = acc[r][0] + bvq.x;
    res.y = acc[r][1] + bvq.y;
    res.z = acc[r][2] + bvq.z;
    res.w = acc[r][3] + bvq.w;
    *(float4*)&out[(size_t)bi * DM + o0] = res;
  }
}

extern "C" void kernel_launch(void* const* d_in, const int* in_sizes, int n_in,
                              void* d_out, int out_size, void* d_ws, size_t ws_size,
                              hipStream_t stream) {
  const float* x      = (const float*)d_in[0];
  const float* coords = (const float*)d_in[1];
  const float* Wqkv   = (const float*)d_in[2];
  const float* bqkv   = (const float*)d_in[3];
  const float* Wb1    = (const float*)d_in[4];
  const float* bb1    = (const float*)d_in[5];
  const float* Wb2    = (const float*)d_in[6];
  // d_in[7] = bb2: softmax-invariant, unused
  const float* Wv1    = (const float*)d_in[8];
  const float* bv1    = (const float*)d_in[9];
  const float* Wv2    = (const float*)d_in[10];
  const float* bv2    = (const float*)d_in[11];
  float* outp = (float*)d_out;
  float* ws = (float*)d_ws;

  const size_t SZ = (size_t)BATCH * NTOK * DM;       // 262144 floats
  const size_t WSM_SZ = (size_t)BATCH * NH * NTOK * NTOK;  // 1048576 floats
  float* Qw    = ws;
  float* Kw    = ws + SZ;
  float* Sbw   = ws + 2 * SZ;
  float* Svw   = ws + 3 * SZ;
  float* Vw    = ws + 4 * SZ;
  float* Wb2T  = ws + 5 * SZ;                        // 4096 floats
  float* Wsm   = ws + 5 * SZ + 4096;                 // 1048576 floats
  ushort16* Gbf  = (ushort16*)(ws + 5 * SZ + 4096 + WSM_SZ);          // 2097152 ushorts
  ushort16* PbT8 = (ushort16*)(ws + 5 * SZ + 4096 + 2 * WSM_SZ);      // 262144 ushorts
  ushort16* PvQ  = (ushort16*)(ws + 5 * SZ + 4096 + 2 * WSM_SZ + SZ / 2);

  hipLaunchKernelGGL(prep_pe, dim3((BATCH * NTOK * DM) / 256), dim3(256), 0, stream,
                     coords, Wb1, bb1, Wv1, bv1, Wb2,
                     Sbw, Svw, PbT8, PvQ, Wb2T);
  hipLaunchKernelGGL(qkv_gemm, dim3(8, 24), dim3(256), 0, stream,
                     x, Wqkv, bqkv, Qw, Kw, Vw);
  hipLaunchKernelGGL(attn_part, dim3(BATCH * NTOK), dim3(512), 0, stream,
                     Qw, Kw, Sbw, Svw, PbT8, PvQ, Wb2T, Wsm, Gbf);
  hipLaunchKernelGGL(out_gemm, dim3(8, 8), dim3(256), 0, stream,
                     Gbf, Wsm, Wv2, Vw, bv2, outp);
}